// Round 10
// baseline (103.189 us; speedup 1.0000x reference)
//
#include <hip/hip_runtime.h>
#include <hip/hip_bf16.h>

// theta[i,j,k] = sum_d W[i,d] V[j,d] U[k,d];  out = sigmoid(theta)
// I=1024, J=512, K=256, D=64.  GEMM view, swapped MFMA operands (A=U, B=WV):
// lane holds a k-quad of one m-row.  R9 topology kept: per-wave contiguous
// 64 KB span, XCD-contiguous 64 MB regions, 256 B-segment stores, 12 waves/CU.
// This round's single change: COMPUTE HOIST -- all 16 k-tiles accumulated in
// registers first, then the 4 transpose/store phases run back-to-back, so the
// wave's 16 KB store window is revisited within ~100 cycles (L2 lines still
// resident -> full-line merge) instead of across 4 compute phases.

#define NI 1024
#define NJ 512
#define NK 256
#define ND 64

typedef __attribute__((ext_vector_type(8))) __bf16 bf16x8;
typedef __attribute__((ext_vector_type(4))) float   f32x4;

constexpr int LDU  = ND + 8;               // U row stride 144 B
constexpr int GRID = 2048;                 // 2048 blocks x 256 rows = all 512K m-rows

__global__ __launch_bounds__(256) void ltf_kernel(
    const float* __restrict__ W, const float* __restrict__ V,
    const float* __restrict__ U, float* __restrict__ out)
{
    __shared__ __bf16 Ulds[NK][LDU];                   // 36,864 B
    __shared__ __align__(16) float tbuf[4][16][64];    // 16,384 B (4 KB/wave, wave-private)
    // total 53,248 B -> 3 blocks/CU, 12 waves/CU

    const int tid  = threadIdx.x;
    const int lane = tid & 63;
    const int wave = tid >> 6;

    // ---- Stage U (f32 -> bf16) into LDS once per block ----
    #pragma unroll
    for (int p = 0; p < 8; ++p) {
        int flat = p * 2048 + tid * 8;
        int r    = flat >> 6;
        int dd   = flat & 63;
        const float* src = U + r * ND + dd;
        f32x4 u0 = *reinterpret_cast<const f32x4*>(src);
        f32x4 u1 = *reinterpret_cast<const f32x4*>(src + 4);
        bf16x8 b;
        #pragma unroll
        for (int t = 0; t < 4; ++t) {
            b[t]     = (__bf16)u0[t];
            b[4 + t] = (__bf16)u1[t];
        }
        *reinterpret_cast<bf16x8*>(&Ulds[r][dd]) = b;
    }
    __syncthreads();

    // MFMA 16x16x32 lane geometry (m89-verified):
    //   A operand (U):  row = lane&15 (-> k in tile), d = (lane>>4)*8 + t
    //   B operand (WV): row = lane&15 (-> m),         d = (lane>>4)*8 + t
    //   D: col = lane&15 (-> m), row = (lane>>4)*4 + r (-> k quad)
    const int arow = lane & 15;
    const int dgrp = lane >> 4;
    const int d0   = dgrp * 8;

    // ---- XCD-contiguous block swizzle (bijective: 2048 = 8 * 256) ----
    const int span   = (blockIdx.x & 7) * 256 + (blockIdx.x >> 3);
    const int mb_blk = span * 256;             // block's 256 consecutive m-rows
    const int i      = span >> 1;              // W row, constant per block
    const int mw     = mb_blk + wave * 64;     // wave's contiguous 64-row span

    const float* wrow = W + i * ND;
    f32x4 wA0 = *reinterpret_cast<const f32x4*>(wrow + d0);
    f32x4 wA1 = *reinterpret_cast<const f32x4*>(wrow + d0 + 4);
    f32x4 wB0 = *reinterpret_cast<const f32x4*>(wrow + d0 + 32);
    f32x4 wB1 = *reinterpret_cast<const f32x4*>(wrow + d0 + 36);

    for (int s = 0; s < 4; ++s) {              // 4 sequential 16-row sub-chunks
        const int ms = mw + s * 16;            // sub-chunk base m-row
        const int j  = (ms & (NJ - 1)) + arow; // lane's V row

        const float* vrow = V + j * ND;
        f32x4 vA0 = *reinterpret_cast<const f32x4*>(vrow + d0);
        f32x4 vA1 = *reinterpret_cast<const f32x4*>(vrow + d0 + 4);
        f32x4 vB0 = *reinterpret_cast<const f32x4*>(vrow + d0 + 32);
        f32x4 vB1 = *reinterpret_cast<const f32x4*>(vrow + d0 + 36);

        bf16x8 wv0, wv1;                       // B operand: d {0..7}/{32..39} (+d0)
        #pragma unroll
        for (int t = 0; t < 4; ++t) {
            wv0[t]     = (__bf16)(wA0[t] * vA0[t]);
            wv0[4 + t] = (__bf16)(wA1[t] * vA1[t]);
            wv1[t]     = (__bf16)(wB0[t] * vB0[t]);
            wv1[4 + t] = (__bf16)(wB1[t] * vB1[t]);
        }

        // ---- Compute + sigmoid ALL 16 k-tiles into registers (64 VGPR) ----
        f32x4 acc[16];
        #pragma unroll
        for (int nt = 0; nt < 16; ++nt) {
            const int n0 = nt * 16;
            bf16x8 u0 = *reinterpret_cast<const bf16x8*>(&Ulds[n0 + arow][d0]);
            bf16x8 u1 = *reinterpret_cast<const bf16x8*>(&Ulds[n0 + arow][32 + d0]);
            f32x4 a = {0.f, 0.f, 0.f, 0.f};
            a = __builtin_amdgcn_mfma_f32_16x16x32_bf16(u0, wv0, a, 0, 0, 0);
            a = __builtin_amdgcn_mfma_f32_16x16x32_bf16(u1, wv1, a, 0, 0, 0);

            // sigmoid(x) ~= 0.5 + x*(1/4 - x^2/48 + x^4/480); |x| <~ 0.5 -> err < 2e-5
            f32x4 sg;
            #pragma unroll
            for (int r = 0; r < 4; ++r) {
                float x  = a[r];
                float x2 = x * x;
                float p  = __builtin_fmaf(x2, 2.0833333e-3f, -2.0833333e-2f);
                p        = __builtin_fmaf(x2, p, 0.25f);
                sg[r]    = __builtin_fmaf(x, p, 0.5f);
            }
            acc[nt] = sg;
        }

        // ---- Back-to-back 4-phase transpose/store (store window hot in L2) ----
        float* obase = out + (size_t)(ms + dgrp) * NK + arow * 4;
        #pragma unroll
        for (int g = 0; g < 4; ++g) {
            #pragma unroll
            for (int t = 0; t < 4; ++t) {
                // XOR-swizzled wave-private transpose write (16 B units)
                const int kf = (t * 16 + dgrp * 4) ^ ((arow & 7) << 2);
                *reinterpret_cast<f32x4*>(&tbuf[wave][arow][kf]) = acc[g * 4 + t];
            }
            // wave-private buffer, unconditional full-wave writes:
            // in-order LDS + compiler lgkmcnt cover the cross-lane handoff.

            // Transposed read + store: 1 instr = 4 consecutive rows x 256 B
            // contiguous segments (plain stores; nt regressed in R8).
            #pragma unroll
            for (int r2 = 0; r2 < 4; ++r2) {
                const int row = r2 * 4 + dgrp;
                const int kf  = (arow * 4) ^ ((row & 7) << 2);
                f32x4 v = *reinterpret_cast<const f32x4*>(&tbuf[wave][row][kf]);
                *reinterpret_cast<f32x4*>(obase + r2 * 4 * NK + g * 64) = v;
            }
        }
    }
}

extern "C" void kernel_launch(void* const* d_in, const int* in_sizes, int n_in,
                              void* d_out, int out_size, void* d_ws, size_t ws_size,
                              hipStream_t stream) {
    const float* W = (const float*)d_in[0];   // [1024,64]
    const float* V = (const float*)d_in[1];   // [512,64]
    const float* U = (const float*)d_in[2];   // [256,64]
    float* out = (float*)d_out;               // [1024,512,256]

    ltf_kernel<<<GRID, 256, 0, stream>>>(W, V, U, out);
}

// Round 11
// 98.035 us; speedup vs baseline: 1.0526x; 1.0526x over previous
//
#include <hip/hip_runtime.h>
#include <hip/hip_bf16.h>

// theta[i,j,k] = sum_d W[i,d] V[j,d] U[k,d];  out = sigmoid(theta)
// I=1024, J=512, K=256, D=64.  GEMM view, swapped MFMA operands (A=U, B=WV):
// lane holds a k-quad of one m-row.  BEST CONFIG (R9, 98.6us):
//  - U staged once in LDS (bf16, padded rows), 12 waves/CU
//  - per-wave 4KB LDS transpose -> 4 rows x 256 B contiguous segments/store
//  - store phases interleaved with MFMA groups (smooth store issue; hoisting
//    them together regressed in R10), no barriers, plain stores (nt regressed)
//  - monotone store topology: wave owns contiguous 64 KB span, block 256 KB,
//    XCD-swizzled so each XCD writes one contiguous 64 MB region.

#define NI 1024
#define NJ 512
#define NK 256
#define ND 64

typedef __attribute__((ext_vector_type(8))) __bf16 bf16x8;
typedef __attribute__((ext_vector_type(4))) float   f32x4;

constexpr int LDU  = ND + 8;               // U row stride 144 B
constexpr int GRID = 2048;                 // 2048 blocks x 256 rows = all 512K m-rows

__global__ __launch_bounds__(256) void ltf_kernel(
    const float* __restrict__ W, const float* __restrict__ V,
    const float* __restrict__ U, float* __restrict__ out)
{
    __shared__ __bf16 Ulds[NK][LDU];                   // 36,864 B
    __shared__ __align__(16) float tbuf[4][16][64];    // 16,384 B (4 KB/wave, wave-private)
    // total 53,248 B -> 3 blocks/CU, 12 waves/CU

    const int tid  = threadIdx.x;
    const int lane = tid & 63;
    const int wave = tid >> 6;

    // ---- Stage U (f32 -> bf16) into LDS once per block ----
    #pragma unroll
    for (int p = 0; p < 8; ++p) {
        int flat = p * 2048 + tid * 8;
        int r    = flat >> 6;
        int dd   = flat & 63;
        const float* src = U + r * ND + dd;
        f32x4 u0 = *reinterpret_cast<const f32x4*>(src);
        f32x4 u1 = *reinterpret_cast<const f32x4*>(src + 4);
        bf16x8 b;
        #pragma unroll
        for (int t = 0; t < 4; ++t) {
            b[t]     = (__bf16)u0[t];
            b[4 + t] = (__bf16)u1[t];
        }
        *reinterpret_cast<bf16x8*>(&Ulds[r][dd]) = b;
    }
    __syncthreads();

    // MFMA 16x16x32 lane geometry (m89-verified):
    //   A operand (U):  row = lane&15 (-> k in tile), d = (lane>>4)*8 + t
    //   B operand (WV): row = lane&15 (-> m),         d = (lane>>4)*8 + t
    //   D: col = lane&15 (-> m), row = (lane>>4)*4 + r (-> k quad)
    const int arow = lane & 15;
    const int dgrp = lane >> 4;
    const int d0   = dgrp * 8;

    // ---- XCD-contiguous block swizzle (bijective: 2048 = 8 * 256) ----
    // XCD x = blockIdx.x % 8 owns contiguous spans [x*256, (x+1)*256).
    const int span   = (blockIdx.x & 7) * 256 + (blockIdx.x >> 3);
    const int mb_blk = span * 256;             // block's 256 consecutive m-rows
    const int i      = span >> 1;              // W row, constant per block
    const int mw     = mb_blk + wave * 64;     // wave's contiguous 64-row span

    const float* wrow = W + i * ND;
    f32x4 wA0 = *reinterpret_cast<const f32x4*>(wrow + d0);
    f32x4 wA1 = *reinterpret_cast<const f32x4*>(wrow + d0 + 4);
    f32x4 wB0 = *reinterpret_cast<const f32x4*>(wrow + d0 + 32);
    f32x4 wB1 = *reinterpret_cast<const f32x4*>(wrow + d0 + 36);

    for (int s = 0; s < 4; ++s) {              // 4 sequential 16-row sub-chunks
        const int ms = mw + s * 16;            // sub-chunk base m-row
        const int j  = (ms & (NJ - 1)) + arow; // lane's V row

        const float* vrow = V + j * ND;
        f32x4 vA0 = *reinterpret_cast<const f32x4*>(vrow + d0);
        f32x4 vA1 = *reinterpret_cast<const f32x4*>(vrow + d0 + 4);
        f32x4 vB0 = *reinterpret_cast<const f32x4*>(vrow + d0 + 32);
        f32x4 vB1 = *reinterpret_cast<const f32x4*>(vrow + d0 + 36);

        bf16x8 wv0, wv1;                       // B operand: d {0..7}/{32..39} (+d0)
        #pragma unroll
        for (int t = 0; t < 4; ++t) {
            wv0[t]     = (__bf16)(wA0[t] * vA0[t]);
            wv0[4 + t] = (__bf16)(wA1[t] * vA1[t]);
            wv1[t]     = (__bf16)(wB0[t] * vB0[t]);
            wv1[4 + t] = (__bf16)(wB1[t] * vB1[t]);
        }

        float* obase = out + (size_t)(ms + dgrp) * NK + arow * 4;

        #pragma unroll
        for (int g = 0; g < 4; ++g) {          // k-group: 64 k values
            f32x4 acc[4];
            #pragma unroll
            for (int t = 0; t < 4; ++t) {      // nt = g*4 + t
                const int n0 = (g * 4 + t) * 16;
                bf16x8 u0 = *reinterpret_cast<const bf16x8*>(&Ulds[n0 + arow][d0]);
                bf16x8 u1 = *reinterpret_cast<const bf16x8*>(&Ulds[n0 + arow][32 + d0]);
                f32x4 a = {0.f, 0.f, 0.f, 0.f};
                a = __builtin_amdgcn_mfma_f32_16x16x32_bf16(u0, wv0, a, 0, 0, 0);
                a = __builtin_amdgcn_mfma_f32_16x16x32_bf16(u1, wv1, a, 0, 0, 0);
                acc[t] = a;
            }

            // sigmoid(x) ~= 0.5 + x*(1/4 - x^2/48 + x^4/480); |x| <~ 0.5 -> err < 2e-5
            #pragma unroll
            for (int t = 0; t < 4; ++t) {
                f32x4 sg;
                #pragma unroll
                for (int r = 0; r < 4; ++r) {
                    float x  = acc[t][r];
                    float x2 = x * x;
                    float p  = __builtin_fmaf(x2, 2.0833333e-3f, -2.0833333e-2f);
                    p        = __builtin_fmaf(x2, p, 0.25f);
                    sg[r]    = __builtin_fmaf(x, p, 0.5f);
                }
                // XOR-swizzled wave-private transpose write (16 B units)
                const int kf = (t * 16 + dgrp * 4) ^ ((arow & 7) << 2);
                *reinterpret_cast<f32x4*>(&tbuf[wave][arow][kf]) = sg;
            }
            // wave-private buffer, unconditional full-wave writes:
            // in-order LDS + compiler lgkmcnt cover the cross-lane handoff.

            // Transposed read + store: 1 instr = 4 consecutive rows x 256 B
            // contiguous segments (plain stores).
            #pragma unroll
            for (int r2 = 0; r2 < 4; ++r2) {
                const int row = r2 * 4 + dgrp;
                const int kf  = (arow * 4) ^ ((row & 7) << 2);
                f32x4 v = *reinterpret_cast<const f32x4*>(&tbuf[wave][row][kf]);
                *reinterpret_cast<f32x4*>(obase + r2 * 4 * NK + g * 64) = v;
            }
        }
    }
}

extern "C" void kernel_launch(void* const* d_in, const int* in_sizes, int n_in,
                              void* d_out, int out_size, void* d_ws, size_t ws_size,
                              hipStream_t stream) {
    const float* W = (const float*)d_in[0];   // [1024,64]
    const float* V = (const float*)d_in[1];   // [512,64]
    const float* U = (const float*)d_in[2];   // [256,64]
    float* out = (float*)d_out;               // [1024,512,256]

    ltf_kernel<<<GRID, 256, 0, stream>>>(W, V, U, out);
}